// Round 9
// baseline (366.786 us; speedup 1.0000x reference)
//
#include <hip/hip_runtime.h>
#include <hip/hip_bf16.h>
#include <cstdint>
#include <cstddef>

#define SEQ    4096
#define DM     2048
#define DH     128
#define NH     16
#define NKV    4
#define NC     3072          // qkv output columns: 2048 q | 512 k | 512 v
#define KOFF   2048
#define VOFF   2560
// 1/sqrt(128) * log2(e): q pre-scale so softmax runs in base-2 (exp2)
#define Q_SCALE 0.12751730f

using bf16 = __hip_bfloat16;
typedef __bf16 bf16x8 __attribute__((ext_vector_type(8)));
typedef float f32x4 __attribute__((ext_vector_type(4)));
typedef float f32x16 __attribute__((ext_vector_type(16)));

static __device__ inline float bf2f(bf16 x) { return __bfloat162float(x); }
static __device__ inline bf16 f2bf(float x) { return __float2bfloat16(x); }

// async global->LDS, 16B per lane. LDS dest = wave-uniform base + lane*16.
static __device__ inline void load_lds16(const bf16* g, bf16* l) {
    __builtin_amdgcn_global_load_lds(
        (const __attribute__((address_space(1))) uint32_t*)g,
        (__attribute__((address_space(3))) uint32_t*)l, 16, 0, 0);
}

// ---------------- x: f32 -> bf16 ----------------
__global__ void xconv(const float* __restrict__ in, bf16* __restrict__ out) {
    int i = blockIdx.x * 256 + threadIdx.x;   // one float4 per thread
    float4 v = ((const float4*)in)[i];
    bf16 a = f2bf(v.x), b = f2bf(v.y), c = f2bf(v.z), d = f2bf(v.w);
    ushort4 u;
    u.x = *(unsigned short*)&a; u.y = *(unsigned short*)&b;
    u.z = *(unsigned short*)&c; u.w = *(unsigned short*)&d;
    ((ushort4*)out)[i] = u;
}

// ---------------- prep: LDS-tiled weight transposes (f32 -> bf16) ----------------
__global__ void prep_wqkv(const float* __restrict__ WQ, const float* __restrict__ WK,
                          const float* __restrict__ WV, bf16* __restrict__ wt) {
    __shared__ float tl[64][65];
    const int t = threadIdx.x;
    const int m0 = (int)blockIdx.x * 64;            // m-tile
    const int head = (int)blockIdx.y >> 1;          // 0..23 = Q0..15,K0..3,V0..3
    const int h0 = ((int)blockIdx.y & 1) * 64;      // h-tile
    const float* src = (head < 16) ? WQ + (size_t)head * DM * DH
                     : (head < 20) ? WK + (size_t)(head - 16) * DM * DH
                                   : WV + (size_t)(head - 20) * DM * DH;
    {
        const int r = t >> 2, c = (t & 3) * 16;
        const float* p = src + (size_t)(m0 + r) * DH + h0 + c;
        #pragma unroll
        for (int kk = 0; kk < 4; ++kk) {
            float4 v = *(const float4*)(p + kk * 4);
            tl[r][c + kk * 4 + 0] = v.x; tl[r][c + kk * 4 + 1] = v.y;
            tl[r][c + kk * 4 + 2] = v.z; tl[r][c + kk * 4 + 3] = v.w;
        }
    }
    __syncthreads();
    {
        const int hh = t >> 2, ms = (t & 3) * 16;
        const int j = head * 128 + h0 + hh;         // concat row (Q|K|V)
        bf16 tmp[16];
        #pragma unroll
        for (int i = 0; i < 16; ++i) tmp[i] = f2bf(tl[ms + i][hh]);
        bf16* q = wt + (size_t)j * DM + m0 + ms;
        *(bf16x8*)q       = *(bf16x8*)&tmp[0];
        *(bf16x8*)(q + 8) = *(bf16x8*)&tmp[8];
    }
}

__global__ void prep_wo(const float* __restrict__ WO, bf16* __restrict__ wt) {
    __shared__ float tl[64][65];
    const int t = threadIdx.x;
    const int m0 = (int)blockIdx.x * 64;   // WO row tile ((n,h) dim)
    const int j0 = (int)blockIdx.y * 64;   // WO col tile (d_model)
    {
        const int r = t >> 2, c = (t & 3) * 16;
        const float* p = WO + (size_t)(m0 + r) * DM + j0 + c;
        #pragma unroll
        for (int kk = 0; kk < 4; ++kk) {
            float4 v = *(const float4*)(p + kk * 4);
            tl[r][c + kk * 4 + 0] = v.x; tl[r][c + kk * 4 + 1] = v.y;
            tl[r][c + kk * 4 + 2] = v.z; tl[r][c + kk * 4 + 3] = v.w;
        }
    }
    __syncthreads();
    {
        const int hh = t >> 2, ms = (t & 3) * 16;
        bf16 tmp[16];
        #pragma unroll
        for (int i = 0; i < 16; ++i) tmp[i] = f2bf(tl[ms + i][hh]);
        bf16* q = wt + (size_t)(j0 + hh) * DM + m0 + ms;
        *(bf16x8*)q       = *(bf16x8*)&tmp[0];
        *(bf16x8*)(q + 8) = *(bf16x8*)&tmp[8];
    }
}

__global__ void prep_bias(const float* __restrict__ bQ, const float* __restrict__ bK,
                          const float* __restrict__ bV, float* __restrict__ bias) {
    int j = blockIdx.x * 256 + threadIdx.x;
    if (j >= NC) return;
    bias[j] = (j < KOFF) ? bQ[j] : (j < VOFF ? bK[j - KOFF] : bV[j - VOFF]);
}

// ---------------- rotary cos/sin table ----------------
__global__ void sctab(float2* __restrict__ tab) {
    int idx = blockIdx.x * 256 + threadIdx.x;   // 0..262143
    int s = idx >> 6, i = idx & 63;
    float inv_freq = __expf(-(float)i * 0.14391156831212788f);
    float ang = (float)s * inv_freq;
    float2 cs;
    cs.x = cosf(ang);
    cs.y = sinf(ang);
    tab[idx] = cs;
}

// ---------------- GEMM 8-phase 256x256 (T2+T3+T4+T5 stack) ----------------
// C[M][N] = A[M][2048] * Bt[N][2048]^T + bias.  512 thr = 8 waves (2M x 4N);
// per-wave output 128x64 (8x4 frags of 16x16).  BK=64, double-buffered 128KB LDS,
// 1 block/CU.  Per K-tile: 4 phases, each {ds_read new frags | issue 2
// global_load_lds for t+1 | raw s_barrier | lgkmcnt(0)+sched_barrier | setprio(1)
// 16 MFMA setprio(0) | s_barrier}; ONE vmcnt(0) per K-tile (phase 3) -- loads
// stay in flight across phase barriers (raw s_barrier, NOT __syncthreads, so no
// compiler-forced vmcnt(0) drain = the m97 stall).  Bank conflicts: XOR involution
// (source slot ^= row&7 on stage, same XOR on ds_read) -- T2's function.
// ROT=1: fused rotary epilogue (KOFF/VOFF are 256-aligned -> block-uniform).
#define G8_NT (DM / 64)   // 32 K-tiles

template <typename OutT, int ROT>
__global__ __launch_bounds__(512, 2)
void gemm8(const bf16* __restrict__ A, const bf16* __restrict__ Bt,
           const float* __restrict__ bias, OutT* __restrict__ C, int N,
           const float2* __restrict__ tab) {
    __shared__ __align__(16) bf16 smem[65536];   // 128 KB: 2 x (A[256][64] | B[256][64])
    const int tid = threadIdx.x;
    const int wave = tid >> 6, lane = tid & 63;
    const int quad = lane >> 4, l15 = lane & 15;
    const int wr = wave >> 2, wc = wave & 3;
    const int m0 = blockIdx.y * 256, n0 = blockIdx.x * 256;
    const int rsw = l15 & 7;

    // staging: waves 0-3 -> A rows [sw*64,+64); waves 4-7 -> B rows; 8 chunks/wave/tile
    const int sw = wave & 3;
    const bf16* gsrc = (wave < 4) ? A + (size_t)(m0 + sw * 64) * DM
                                  : Bt + (size_t)(n0 + sw * 64) * DM;
    const int lrow = lane >> 3;
    const bf16* gp = gsrc + (size_t)lrow * DM + (((lane & 7) ^ lrow) * 8);
    bf16* sbase = smem + (wave < 4 ? 0 : 16384) + sw * 4096;

    f32x4 acc[8][4] = {};

    // prologue: stage tile 0 into buf 0 (full drain once is fine here)
    #pragma unroll
    for (int c = 0; c < 8; ++c)
        load_lds16(gp + (size_t)c * 8 * DM, sbase + c * 512);
    __syncthreads();

    #pragma unroll 1
    for (int t = 0; t < G8_NT; ++t) {
        const int cur = t & 1;
        const bf16* Ab = smem + cur * 32768;
        const bf16* Bb = Ab + 16384;
        bf16* sdst = sbase + (cur ^ 1) * 32768;
        const bool pf = (t + 1 < G8_NT);
        const bf16* gpt = gp + (size_t)(t + 1) * 64;

        bf16x8 aR[4][2], bR[2][2];

        // ---- phase 0: read A[0..3] + B[0..1]; stage c0,c1; mfma acc[0..3][0..1]
        #pragma unroll
        for (int mf = 0; mf < 4; ++mf)
            #pragma unroll
            for (int k = 0; k < 2; ++k)
                aR[mf][k] = *(const bf16x8*)&Ab[(wr * 128 + mf * 16 + l15) * 64 + (((k * 4 + quad) ^ rsw) * 8)];
        #pragma unroll
        for (int nf = 0; nf < 2; ++nf)
            #pragma unroll
            for (int k = 0; k < 2; ++k)
                bR[nf][k] = *(const bf16x8*)&Bb[(wc * 64 + nf * 16 + l15) * 64 + (((k * 4 + quad) ^ rsw) * 8)];
        if (pf) { load_lds16(gpt + (size_t)0 * 8 * DM, sdst + 0 * 512);
                  load_lds16(gpt + (size_t)1 * 8 * DM, sdst + 1 * 512); }
        __builtin_amdgcn_s_barrier();
        asm volatile("s_waitcnt lgkmcnt(0)" ::: "memory");
        __builtin_amdgcn_sched_barrier(0);
        __builtin_amdgcn_s_setprio(1);
        #pragma unroll
        for (int mf = 0; mf < 4; ++mf)
            #pragma unroll
            for (int nf = 0; nf < 2; ++nf)
                #pragma unroll
                for (int k = 0; k < 2; ++k)
                    acc[mf][nf] = __builtin_amdgcn_mfma_f32_16x16x32_bf16(aR[mf][k], bR[nf][k], acc[mf][nf], 0, 0, 0);
        __builtin_amdgcn_s_setprio(0);
        __builtin_amdgcn_s_barrier();

        // ---- phase 1: read B[2..3]; stage c2,c3; mfma acc[0..3][2..3]
        #pragma unroll
        for (int nf = 0; nf < 2; ++nf)
            #pragma unroll
            for (int k = 0; k < 2; ++k)
                bR[nf][k] = *(const bf16x8*)&Bb[(wc * 64 + (2 + nf) * 16 + l15) * 64 + (((k * 4 + quad) ^ rsw) * 8)];
        if (pf) { load_lds16(gpt + (size_t)2 * 8 * DM, sdst + 2 * 512);
                  load_lds16(gpt + (size_t)3 * 8 * DM, sdst + 3 * 512); }
        __builtin_amdgcn_s_barrier();
        asm volatile("s_waitcnt lgkmcnt(0)" ::: "memory");
        __builtin_amdgcn_sched_barrier(0);
        __builtin_amdgcn_s_setprio(1);
        #pragma unroll
        for (int mf = 0; mf < 4; ++mf)
            #pragma unroll
            for (int nf = 0; nf < 2; ++nf)
                #pragma unroll
                for (int k = 0; k < 2; ++k)
                    acc[mf][2 + nf] = __builtin_amdgcn_mfma_f32_16x16x32_bf16(aR[mf][k], bR[nf][k], acc[mf][2 + nf], 0, 0, 0);
        __builtin_amdgcn_s_setprio(0);
        __builtin_amdgcn_s_barrier();

        // ---- phase 2: read A[4..7]; stage c4,c5; mfma acc[4..7][2..3]
        #pragma unroll
        for (int mf = 0; mf < 4; ++mf)
            #pragma unroll
            for (int k = 0; k < 2; ++k)
                aR[mf][k] = *(const bf16x8*)&Ab[(wr * 128 + (4 + mf) * 16 + l15) * 64 + (((k * 4 + quad) ^ rsw) * 8)];
        if (pf) { load_lds16(gpt + (size_t)4 * 8 * DM, sdst + 4 * 512);
                  load_lds16(gpt + (size_t)5 * 8 * DM, sdst + 5 * 512); }
        __builtin_amdgcn_s_barrier();
        asm volatile("s_waitcnt lgkmcnt(0)" ::: "memory");
        __builtin_amdgcn_sched_barrier(0);
        __builtin_amdgcn_s_setprio(1);
        #pragma unroll
        for (int mf = 0; mf < 4; ++mf)
            #pragma unroll
            for (int nf = 0; nf < 2; ++nf)
                #pragma unroll
                for (int k = 0; k < 2; ++k)
                    acc[4 + mf][2 + nf] = __builtin_amdgcn_mfma_f32_16x16x32_bf16(aR[mf][k], bR[nf][k], acc[4 + mf][2 + nf], 0, 0, 0);
        __builtin_amdgcn_s_setprio(0);
        __builtin_amdgcn_s_barrier();

        // ---- phase 3: read B[0..1]; stage c6,c7; mfma acc[4..7][0..1]; tile-end vmcnt(0)
        #pragma unroll
        for (int nf = 0; nf < 2; ++nf)
            #pragma unroll
            for (int k = 0; k < 2; ++k)
                bR[nf][k] = *(const bf16x8*)&Bb[(wc * 64 + nf * 16 + l15) * 64 + (((k * 4 + quad) ^ rsw) * 8)];
        if (pf) { load_lds16(gpt + (size_t)6 * 8 * DM, sdst + 6 * 512);
                  load_lds16(gpt + (size_t)7 * 8 * DM, sdst + 7 * 512); }
        __builtin_amdgcn_s_barrier();
        asm volatile("s_waitcnt lgkmcnt(0)" ::: "memory");
        __builtin_amdgcn_sched_barrier(0);
        __builtin_amdgcn_s_setprio(1);
        #pragma unroll
        for (int mf = 0; mf < 4; ++mf)
            #pragma unroll
            for (int nf = 0; nf < 2; ++nf)
                #pragma unroll
                for (int k = 0; k < 2; ++k)
                    acc[4 + mf][nf] = __builtin_amdgcn_mfma_f32_16x16x32_bf16(aR[mf][k], bR[nf][k], acc[4 + mf][nf], 0, 0, 0);
        __builtin_amdgcn_s_setprio(0);
        asm volatile("s_waitcnt vmcnt(0)" ::: "memory");   // tile t+1 loads landed
        __builtin_amdgcn_sched_barrier(0);
        __builtin_amdgcn_s_barrier();
    }

    // ---- epilogue: bias (+rotary) + C write ----
    const bool doRot = ROT && (n0 < VOFF);
    const float scl = (n0 < KOFF) ? Q_SCALE : 1.0f;
    #pragma unroll
    for (int mf = 0; mf < 8; ++mf) {
        int row = m0 + wr * 128 + mf * 16 + quad * 4;
        #pragma unroll
        for (int nf = 0; nf < 4; ++nf) {
            int col = n0 + wc * 64 + nf * 16 + l15;
            float bv = bias[col];
            if (ROT && doRot) {
                const int ii = (col >> 1) & 63;
                const bool odd = col & 1;
                #pragma unroll
                for (int r = 0; r < 4; ++r) {
                    float v = acc[mf][nf][r] + bv;
                    float pv = __shfl_xor(v, 1);
                    float2 cs = tab[((row + r) << 6) + ii];
                    float o = odd ? (pv * cs.y + v * cs.x) : (v * cs.x - pv * cs.y);
                    C[(size_t)(row + r) * N + col] = (OutT)f2bf(o * scl);
                }
            } else {
                #pragma unroll
                for (int r = 0; r < 4; ++r) {
                    float val = acc[mf][nf][r] + bv;
                    if constexpr (sizeof(OutT) == 2)
                        C[(size_t)(row + r) * N + col] = f2bf(val);
                    else
                        C[(size_t)(row + r) * N + col] = val;
                }
            }
        }
    }
}

// ---------------- V transpose via LDS tile: vt[kv][d][s] ----------------
__global__ void vtrans(const bf16* __restrict__ qkv, bf16* __restrict__ vt) {
    __shared__ bf16 tl[64][72];
    const int t = threadIdx.x;
    const int s0 = (int)(blockIdx.x >> 3) * 64;   // seq tile
    const int c0 = (int)(blockIdx.x & 7) * 64;    // v-col tile (kv*128+d space)
    {
        int r = t >> 2, cc = (t & 3) * 16;
        const bf16* p = qkv + (size_t)(s0 + r) * NC + VOFF + c0 + cc;
        *(bf16x8*)&tl[r][cc]     = *(const bf16x8*)p;
        *(bf16x8*)&tl[r][cc + 8] = *(const bf16x8*)(p + 8);
    }
    __syncthreads();
    {
        int dd = t >> 2, sc = (t & 3) * 16;
        int col = c0 + dd;                        // = kv*128 + d
        bf16 tmp[16];
        #pragma unroll
        for (int j = 0; j < 16; ++j) tmp[j] = tl[sc + j][dd];
        bf16* q = vt + (size_t)col * SEQ + s0 + sc;
        *(bf16x8*)q       = *(bf16x8*)&tmp[0];
        *(bf16x8*)(q + 8) = *(bf16x8*)&tmp[8];
    }
}

// ---------------- flash attention v9 (frozen from r8: 110.2 us) ----------------
__global__ __launch_bounds__(256, 3)
void flash(const bf16* __restrict__ qkv, const bf16* __restrict__ vt,
           bf16* __restrict__ z) {
    __shared__ char smem[33280];
    bf16*  Ks  = (bf16*)smem;                    // [64][128]  = 16384 B (swizzled)
    bf16*  Vs  = (bf16*)(smem + 16384);          // [128][64]  = 16384 B (swizzled)
    float* lml = (float*)(smem + 32768);         // 4 x 32     =   512 B
    float* ob  = (float*)smem;                   // merge reuse: 2*32*128 f32 = 32768 B

    const int tid = threadIdx.x;
    const int wave = tid >> 6, lane = tid & 63;
    const int l31 = lane & 31, lh = lane >> 5;
    const int ch = wave >> 1;         // row chunk (16 rows)
    const int kh = wave & 1;          // key half (32 keys)
    const int bx = blockIdx.x;
    const int qt = 127 - (bx >> 3);   // biggest first
    const int g = (bx >> 1) & 3;      // KV group
    const int hp = bx & 1;            // head pair within group
    const int r_base = qt * 32 + ch * 16;
    const int ktmax = qt >> 1;
    const int rsw = l31 & 7;          // read-side XOR (row&7 for both QK and PV reads)

    // staging pointers (3 total; folding: krow&7 repeats every 8 rows, vdd&7 is
    // chunk-independent)
    const int krow0 = wave * 16 + (lane >> 4);          // chunk i=0 row
    const int krow1 = krow0 + 4;                        // chunk i=1 row
    const bf16* kp0 = qkv + KOFF + g * DH + (size_t)krow0 * NC + (((lane & 15) ^ (krow0 & 7)) * 8);
    const bf16* kp1 = qkv + KOFF + g * DH + (size_t)krow1 * NC + (((lane & 15) ^ (krow1 & 7)) * 8);
    const int vdd0 = wave * 32 + (lane >> 3);           // chunk i=0 d-row
    const bf16* vp0 = vt + (size_t)(g * DH + vdd0) * SEQ + (((lane & 7) ^ ((lane >> 3) & 7)) * 8);

    // Q -> registers (B operand): lane n=l31 -> q-row; k = lh*8 + s*16 + j
    bf16x8 qf[8];
    {
        const int qrow = r_base + (l31 & 15);
        const int head = g * 4 + hp * 2 + (l31 >> 4);
        const bf16* qp = qkv + (size_t)qrow * NC + head * DH + lh * 8;
        #pragma unroll
        for (int s = 0; s < 8; ++s)
            qf[s] = *(const bf16x8*)(qp + s * 16);
    }

    f32x16 o_acc[4] = {};
    float lsum = 0.0f;

    for (int kt = 0; kt <= ktmax; ++kt) {
        __syncthreads();   // all waves done reading Ks/Vs of prev iter
        load_lds16(kp0,                        Ks + (wave * 4 + 0) * 512);
        load_lds16(kp1,                        Ks + (wave * 4 + 1) * 512);
        load_lds16(kp0 + (size_t)8 * NC,       Ks + (wave * 4 + 2) * 512);
        load_lds16(kp1 + (size_t)8 * NC,       Ks + (wave * 4 + 3) * 512);
        load_lds16(vp0,                        Vs + (wave * 4 + 0) * 512);
        load_lds16(vp0 + (size_t)8 * SEQ,      Vs + (wave * 4 + 1) * 512);
        load_lds16(vp0 + (size_t)16 * SEQ,     Vs + (wave * 4 + 2) * 512);
        load_lds16(vp0 + (size_t)24 * SEQ,     Vs + (wave * 4 + 3) * 512);
        __syncthreads();   // compiler drains vmcnt(0) before barrier
        kp0 += (size_t)64 * NC; kp1 += (size_t)64 * NC; vp0 += 64;

        const int key_min = kt * 64 + kh * 32;
        if (key_min <= r_base + 15) {   // some key unmasked for this chunk
            // S^T = K Q^T : lane l31 = q-row, regs = 16 keys
            f32x16 sacc = {};
            __builtin_amdgcn_s_setprio(1);
            #pragma unroll
            for (int s = 0; s < 8; ++s) {
                bf16x8 kb = *(const bf16x8*)&Ks[(kh * 32 + l31) * 128 + (((lh + 2 * s) ^ rsw) * 8)];
                sacc = __builtin_amdgcn_mfma_f32_32x32x16_bf16(kb, qf[s], sacc, 0, 0, 0);
            }
            __builtin_amdgcn_s_setprio(0);

            const bool needmask = (key_min + 31 > r_base);
            const int qrow = r_base + (l31 & 15);
            float e[16];
            if (needmask) {   // diagonal tile only (~1 of ~33 iters)
                #pragma unroll
                for (int rg = 0; rg < 16; ++rg) {
                    const int keyg = key_min + (rg & 3) + 8 * (rg >> 2) + 4 * lh;
                    float sv = sacc[rg];
                    if (keyg > qrow) sv = -INFINITY;
                    e[rg] = exp2f(sv);
                }
            } else {
                #pragma unroll
                for (int rg = 0; rg < 16; ++rg)
                    e[rg] = exp2f(sacc[rg]);
            }
            {
                float t0 = (e[0] + e[1]) + (e[2] + e[3]);
                float t1 = (e[4] + e[5]) + (e[6] + e[7]);
                float t2 = (e[8] + e[9]) + (e[10] + e[11]);
                float t3 = (e[12] + e[13]) + (e[14] + e[15]);
                lsum += (t0 + t1) + (t2 + t3);
            }

            // P -> A fragments in-register (T12)
            bf16x8 pa[2];
            #pragma unroll
            for (int s2 = 0; s2 < 2; ++s2) {
                uint32_t wA0, wA1, wB0, wB1;
                asm("v_cvt_pk_bf16_f32 %0, %1, %2" : "=v"(wA0) : "v"(e[8*s2+0]), "v"(e[8*s2+1]));
                asm("v_cvt_pk_bf16_f32 %0, %1, %2" : "=v"(wA1) : "v"(e[8*s2+2]), "v"(e[8*s2+3]));
                asm("v_cvt_pk_bf16_f32 %0, %1, %2" : "=v"(wB0) : "v"(e[8*s2+4]), "v"(e[8*s2+5]));
                asm("v_cvt_pk_bf16_f32 %0, %1, %2" : "=v"(wB1) : "v"(e[8*s2+6]), "v"(e[8*s2+7]));
                asm volatile("v_permlane32_swap_b32 %0, %1" : "+v"(wA0), "+v"(wB0));
                asm volatile("v_permlane32_swap_b32 %0, %1" : "+v"(wA1), "+v"(wB1));
                union { uint32_t u[4]; bf16x8 v; } cvt;
                cvt.u[0] = wA0; cvt.u[1] = wA1; cvt.u[2] = wB0; cvt.u[3] = wB1;
                pa[s2] = cvt.v;
            }

            // PV: A = P fragments (in-reg), B = V^T fragments from LDS
            __builtin_amdgcn_s_setprio(1);
            #pragma unroll
            for (int nt = 0; nt < 4; ++nt) {
                #pragma unroll
                for (int s2 = 0; s2 < 2; ++s2) {
                    bf16x8 vb = *(const bf16x8*)&Vs[(nt * 32 + l31) * 64 + (((kh * 4 + lh + 2 * s2) ^ rsw) * 8)];
                    o_acc[nt] = __builtin_amdgcn_mfma_f32_32x32x16_bf16(pa[s2], vb, o_acc[nt], 0, 0, 0);
                }
            }
            __builtin_amdgcn_s_setprio(0);
        }
    }

    // merge lh halves of l in-register
    float la = lsum, lb = lsum;
    asm volatile("v_permlane32_swap_b32 %0, %1" : "+v"(la), "+v"(lb));
    const float l_tot = la + lb;   // full 32-key-half sum for q-row l31

    // ---- merge key-half partials (linear: no max alignment needed) ----
    __syncthreads();               // all compute done; Ks/Vs region free for ob
    if (lh == 0) lml[wave * 32 + l31] = l_tot;
    if (kh == 1) {
        #pragma unroll
        for (int nt = 0; nt < 4; ++nt)
            #pragma unroll
            for (int rg = 0; rg < 16; ++rg) {
                const int m = (rg & 3) + 8 * (rg >> 2) + 4 * lh;
                ob[(ch * 32 + m) * 128 + nt * 32 + l31] = o_acc[nt][rg];
            }
    }
    __syncthreads();
    if (kh == 0) {
        float invl[16];
        #pragma unroll
        for (int rg = 0; rg < 16; ++rg) {
            const int m = (rg & 3) + 8 * (rg >> 2) + 4 * lh;
            invl[rg] = 1.0f / (lml[wave * 32 + m] + lml[(wave + 1) * 32 + m]);
        }
        #pragma unroll
        for (int nt = 0; nt < 4; ++nt)
            #pragma unroll
            for (int rg = 0; rg < 16; ++rg) {
                const int m = (rg & 3) + 8 * (rg >> 2) + 4 * lh;
                float oo = o_acc[nt][rg] + ob[(ch * 32 + m) * 128 + nt * 32 + l31];
                const int row = r_base + (m & 15);
                const int col = (g * 4 + hp * 2 + (m >> 4)) * DH + nt * 32 + l31;
                z[(size_t)row * DM + col] = f2bf(oo * invl[rg]);
            }
    }
}

// ---------------- launch ----------------
extern "C" void kernel_launch(void* const* d_in, const int* in_sizes, int n_in,
                              void* d_out, int out_size, void* d_ws, size_t ws_size,
                              hipStream_t stream) {
    const float* x  = (const float*)d_in[0];
    const float* WQ = (const float*)d_in[1];
    const float* WK = (const float*)d_in[2];
    const float* WV = (const float*)d_in[3];
    const float* WO = (const float*)d_in[4];
    const float* bQ = (const float*)d_in[5];
    const float* bK = (const float*)d_in[6];
    const float* bV = (const float*)d_in[7];
    const float* bO = (const float*)d_in[8];
    float* out = (float*)d_out;

    char* ws = (char*)d_ws;
    bf16*  wt_cat = (bf16*)(ws);                  // 12,582,912
    bf16*  wt_o   = (bf16*)(ws + 12582912);       //  8,388,608
    float* bias_c = (float*)(ws + 20971520);      //  16,384 (padded)
    bf16*  qkv    = (bf16*)(ws + 20987904);       // 25,165,824
    bf16*  vt     = (bf16*)(ws + 46153728);       //  4,194,304
    bf16*  z      = (bf16*)(ws + 50348032);       // 16,777,216
    bf16*  xb     = (bf16*)(ws + 67125248);       // 16,777,216
    float2* sct   = (float2*)vt;                  // 2,097,152: vt region dead until
                                                  // vtrans, sct dead after gemm1

    xconv    <<<8192, 256, 0, stream>>>(x, xb);
    prep_wqkv<<<dim3(32, 48), 256, 0, stream>>>(WQ, WK, WV, wt_cat);
    prep_wo  <<<dim3(32, 32), 256, 0, stream>>>(WO, wt_o);
    prep_bias<<<12, 256, 0, stream>>>(bQ, bK, bV, bias_c);
    sctab    <<<1024, 256, 0, stream>>>(sct);
    gemm8<bf16, 1> <<<dim3(12, 16), 512, 0, stream>>>(xb, wt_cat, bias_c, qkv, NC, sct);
    vtrans   <<<512, 256, 0, stream>>>(qkv, vt);
    flash    <<<1024, 256, 0, stream>>>(qkv, vt, z);
    gemm8<float, 0><<<dim3(8, 16), 512, 0, stream>>>(z, wt_o, bO, out, DM, nullptr);
}

// Round 10
// 356.987 us; speedup vs baseline: 1.0274x; 1.0274x over previous
//
#include <hip/hip_runtime.h>
#include <hip/hip_bf16.h>
#include <cstdint>
#include <cstddef>

#define SEQ    4096
#define DM     2048
#define DH     128
#define NH     16
#define NKV    4
#define NC     3072          // qkv output columns: 2048 q | 512 k | 512 v
#define KOFF   2048
#define VOFF   2560
// 1/sqrt(128) * log2(e): q pre-scale so softmax runs in base-2 (exp2)
#define Q_SCALE 0.12751730f

using bf16 = __hip_bfloat16;
typedef __bf16 bf16x8 __attribute__((ext_vector_type(8)));
typedef float f32x4 __attribute__((ext_vector_type(4)));
typedef float f32x16 __attribute__((ext_vector_type(16)));

static __device__ inline float bf2f(bf16 x) { return __bfloat162float(x); }
static __device__ inline bf16 f2bf(float x) { return __float2bfloat16(x); }

// async global->LDS, 16B per lane. LDS dest = wave-uniform base + lane*16.
static __device__ inline void load_lds16(const bf16* g, bf16* l) {
    __builtin_amdgcn_global_load_lds(
        (const __attribute__((address_space(1))) uint32_t*)g,
        (__attribute__((address_space(3))) uint32_t*)l, 16, 0, 0);
}

// ---------------- x: f32 -> bf16 ----------------
__global__ void xconv(const float* __restrict__ in, bf16* __restrict__ out) {
    int i = blockIdx.x * 256 + threadIdx.x;   // one float4 per thread
    float4 v = ((const float4*)in)[i];
    bf16 a = f2bf(v.x), b = f2bf(v.y), c = f2bf(v.z), d = f2bf(v.w);
    ushort4 u;
    u.x = *(unsigned short*)&a; u.y = *(unsigned short*)&b;
    u.z = *(unsigned short*)&c; u.w = *(unsigned short*)&d;
    ((ushort4*)out)[i] = u;
}

// ---------------- prep: LDS-tiled weight transposes (f32 -> bf16) ----------------
__global__ void prep_wqkv(const float* __restrict__ WQ, const float* __restrict__ WK,
                          const float* __restrict__ WV, bf16* __restrict__ wt) {
    __shared__ float tl[64][65];
    const int t = threadIdx.x;
    const int m0 = (int)blockIdx.x * 64;            // m-tile
    const int head = (int)blockIdx.y >> 1;          // 0..23 = Q0..15,K0..3,V0..3
    const int h0 = ((int)blockIdx.y & 1) * 64;      // h-tile
    const float* src = (head < 16) ? WQ + (size_t)head * DM * DH
                     : (head < 20) ? WK + (size_t)(head - 16) * DM * DH
                                   : WV + (size_t)(head - 20) * DM * DH;
    {
        const int r = t >> 2, c = (t & 3) * 16;
        const float* p = src + (size_t)(m0 + r) * DH + h0 + c;
        #pragma unroll
        for (int kk = 0; kk < 4; ++kk) {
            float4 v = *(const float4*)(p + kk * 4);
            tl[r][c + kk * 4 + 0] = v.x; tl[r][c + kk * 4 + 1] = v.y;
            tl[r][c + kk * 4 + 2] = v.z; tl[r][c + kk * 4 + 3] = v.w;
        }
    }
    __syncthreads();
    {
        const int hh = t >> 2, ms = (t & 3) * 16;
        const int j = head * 128 + h0 + hh;         // concat row (Q|K|V)
        bf16 tmp[16];
        #pragma unroll
        for (int i = 0; i < 16; ++i) tmp[i] = f2bf(tl[ms + i][hh]);
        bf16* q = wt + (size_t)j * DM + m0 + ms;
        *(bf16x8*)q       = *(bf16x8*)&tmp[0];
        *(bf16x8*)(q + 8) = *(bf16x8*)&tmp[8];
    }
}

__global__ void prep_wo(const float* __restrict__ WO, bf16* __restrict__ wt) {
    __shared__ float tl[64][65];
    const int t = threadIdx.x;
    const int m0 = (int)blockIdx.x * 64;   // WO row tile ((n,h) dim)
    const int j0 = (int)blockIdx.y * 64;   // WO col tile (d_model)
    {
        const int r = t >> 2, c = (t & 3) * 16;
        const float* p = WO + (size_t)(m0 + r) * DM + j0 + c;
        #pragma unroll
        for (int kk = 0; kk < 4; ++kk) {
            float4 v = *(const float4*)(p + kk * 4);
            tl[r][c + kk * 4 + 0] = v.x; tl[r][c + kk * 4 + 1] = v.y;
            tl[r][c + kk * 4 + 2] = v.z; tl[r][c + kk * 4 + 3] = v.w;
        }
    }
    __syncthreads();
    {
        const int hh = t >> 2, ms = (t & 3) * 16;
        bf16 tmp[16];
        #pragma unroll
        for (int i = 0; i < 16; ++i) tmp[i] = f2bf(tl[ms + i][hh]);
        bf16* q = wt + (size_t)(j0 + hh) * DM + m0 + ms;
        *(bf16x8*)q       = *(bf16x8*)&tmp[0];
        *(bf16x8*)(q + 8) = *(bf16x8*)&tmp[8];
    }
}

__global__ void prep_bias(const float* __restrict__ bQ, const float* __restrict__ bK,
                          const float* __restrict__ bV, float* __restrict__ bias) {
    int j = blockIdx.x * 256 + threadIdx.x;
    if (j >= NC) return;
    bias[j] = (j < KOFF) ? bQ[j] : (j < VOFF ? bK[j - KOFF] : bV[j - VOFF]);
}

// ---------------- rotary cos/sin table ----------------
__global__ void sctab(float2* __restrict__ tab) {
    int idx = blockIdx.x * 256 + threadIdx.x;   // 0..262143
    int s = idx >> 6, i = idx & 63;
    float inv_freq = __expf(-(float)i * 0.14391156831212788f);
    float ang = (float)s * inv_freq;
    float2 cs;
    cs.x = cosf(ang);
    cs.y = sinf(ang);
    tab[idx] = cs;
}

// ---------------- GEMM: C[M][N] = A[M][2048] * Bt[N][2048]^T + bias ----------------
// 2-phase 128x128 (proven best at this shape: 768/512 blocks = full CU coverage;
// r9 showed 256-tile 8-phase underfills the grid at M=4096,N<=3072 and loses).
// ROT=1: fused rotary in epilogue.
#define BM 128
#define BN 128
#define BK 64

template <typename OutT, int ROT>
__global__ __launch_bounds__(256)
void gemm_bt(const bf16* __restrict__ A, const bf16* __restrict__ Bt,
             const float* __restrict__ bias, OutT* __restrict__ C, int N,
             const float2* __restrict__ tab) {
    __shared__ __align__(16) bf16 As[BM * BK];   // 16 KB, linear [128][64]
    __shared__ __align__(16) bf16 Bs[BN * BK];   // 16 KB
    const int tid = threadIdx.x;
    const int wave = tid >> 6, lane = tid & 63;
    const int quad = lane >> 4, l15 = lane & 15;
    const int wm = (wave >> 1) * 64, wn = (wave & 1) * 64;
    const int m0 = blockIdx.y * BM, n0 = blockIdx.x * BN;

    f32x4 acc[4][4] = {};

    const bf16* gsrc = (wave < 2)
        ? A  + (size_t)(m0 + (wave & 1) * 64) * DM
        : Bt + (size_t)(n0 + (wave & 1) * 64) * DM;
    bf16* lbase = (wave < 2 ? As : Bs) + (wave & 1) * 64 * BK;
    const int lrow = lane >> 3;                          // 0..7
    const int gslot = (lane & 7) ^ lrow;                 // swizzled source slot
    const bf16* gp = gsrc + (size_t)lrow * DM + gslot * 8;

    const int rsw = l15 & 7;

    for (int k0 = 0; k0 < DM; k0 += BK) {
        __syncthreads();
        #pragma unroll
        for (int cc = 0; cc < 8; ++cc)
            load_lds16(gp + (size_t)cc * 8 * DM + k0, lbase + cc * 8 * BK);
        __syncthreads();

        #pragma unroll
        for (int ks = 0; ks < 2; ++ks) {
            bf16x8 af[4], bfr[4];
            #pragma unroll
            for (int i = 0; i < 4; ++i)
                af[i] = *(const bf16x8*)&As[(wm + i * 16 + l15) * BK + (((ks * 4 + quad) ^ rsw) * 8)];
            #pragma unroll
            for (int j = 0; j < 4; ++j)
                bfr[j] = *(const bf16x8*)&Bs[(wn + j * 16 + l15) * BK + (((ks * 4 + quad) ^ rsw) * 8)];
            #pragma unroll
            for (int i = 0; i < 4; ++i)
                #pragma unroll
                for (int j = 0; j < 4; ++j)
                    acc[i][j] = __builtin_amdgcn_mfma_f32_16x16x32_bf16(af[i], bfr[j], acc[i][j], 0, 0, 0);
        }
    }

    const bool doRot = ROT && (n0 < VOFF);
    const float scl = (n0 < KOFF) ? Q_SCALE : 1.0f;

    #pragma unroll
    for (int i = 0; i < 4; ++i) {
        int row = m0 + wm + i * 16 + quad * 4;
        #pragma unroll
        for (int j = 0; j < 4; ++j) {
            int col = n0 + wn + j * 16 + l15;
            float bv = bias[col];
            if (ROT && doRot) {
                const int ii = (col >> 1) & 63;
                const bool odd = col & 1;
                #pragma unroll
                for (int r = 0; r < 4; ++r) {
                    float v = acc[i][j][r] + bv;
                    float pv = __shfl_xor(v, 1);
                    float2 cs = tab[((row + r) << 6) + ii];
                    float o = odd ? (pv * cs.y + v * cs.x) : (v * cs.x - pv * cs.y);
                    C[(size_t)(row + r) * N + col] = (OutT)f2bf(o * scl);
                }
            } else {
                #pragma unroll
                for (int r = 0; r < 4; ++r) {
                    float val = acc[i][j][r] + bv;
                    if constexpr (sizeof(OutT) == 2)
                        C[(size_t)(row + r) * N + col] = f2bf(val);
                    else
                        C[(size_t)(row + r) * N + col] = val;
                }
            }
        }
    }
}

// ---------------- V transpose via LDS tile: vt[kv][d][s] ----------------
__global__ void vtrans(const bf16* __restrict__ qkv, bf16* __restrict__ vt) {
    __shared__ bf16 tl[64][72];
    const int t = threadIdx.x;
    const int s0 = (int)(blockIdx.x >> 3) * 64;   // seq tile
    const int c0 = (int)(blockIdx.x & 7) * 64;    // v-col tile (kv*128+d space)
    {
        int r = t >> 2, cc = (t & 3) * 16;
        const bf16* p = qkv + (size_t)(s0 + r) * NC + VOFF + c0 + cc;
        *(bf16x8*)&tl[r][cc]     = *(const bf16x8*)p;
        *(bf16x8*)&tl[r][cc + 8] = *(const bf16x8*)(p + 8);
    }
    __syncthreads();
    {
        int dd = t >> 2, sc = (t & 3) * 16;
        int col = c0 + dd;                        // = kv*128 + d
        bf16 tmp[16];
        #pragma unroll
        for (int j = 0; j < 16; ++j) tmp[j] = tl[sc + j][dd];
        bf16* q = vt + (size_t)col * SEQ + s0 + sc;
        *(bf16x8*)q       = *(bf16x8*)&tmp[0];
        *(bf16x8*)(q + 8) = *(bf16x8*)&tmp[8];
    }
}

// ---------------- flash attention v10 (= v9 + QK chain split + PV nt-inner) ----------------
// 1024 blocks x 256 thr; block = (qt, g, hp), biggest-qt-first. 4 waves = 2ch x 2kh.
// K/V via global_load_lds, XOR involution swizzle, swapped QK^T + in-reg P (T12),
// (256,3) cap = 3 blocks/CU (r7/r8: occupancy > spill). v10 isolates v8's two
// compute tweaks on this structure: QK as 2 independent 4-chains (+1 vec add)
// and PV with nt innermost (independent accumulators back-to-back).
__global__ __launch_bounds__(256, 3)
void flash(const bf16* __restrict__ qkv, const bf16* __restrict__ vt,
           bf16* __restrict__ z) {
    __shared__ char smem[33280];
    bf16*  Ks  = (bf16*)smem;                    // [64][128]  = 16384 B (swizzled)
    bf16*  Vs  = (bf16*)(smem + 16384);          // [128][64]  = 16384 B (swizzled)
    float* lml = (float*)(smem + 32768);         // 4 x 32     =   512 B
    float* ob  = (float*)smem;                   // merge reuse: 2*32*128 f32 = 32768 B

    const int tid = threadIdx.x;
    const int wave = tid >> 6, lane = tid & 63;
    const int l31 = lane & 31, lh = lane >> 5;
    const int ch = wave >> 1;         // row chunk (16 rows)
    const int kh = wave & 1;          // key half (32 keys)
    const int bx = blockIdx.x;
    const int qt = 127 - (bx >> 3);   // biggest first
    const int g = (bx >> 1) & 3;      // KV group
    const int hp = bx & 1;            // head pair within group
    const int r_base = qt * 32 + ch * 16;
    const int ktmax = qt >> 1;
    const int rsw = l31 & 7;          // read-side XOR (row&7 for both QK and PV reads)

    // staging pointers (3 total; folding: krow&7 repeats every 8 rows, vdd&7 is
    // chunk-independent)
    const int krow0 = wave * 16 + (lane >> 4);          // chunk i=0 row
    const int krow1 = krow0 + 4;                        // chunk i=1 row
    const bf16* kp0 = qkv + KOFF + g * DH + (size_t)krow0 * NC + (((lane & 15) ^ (krow0 & 7)) * 8);
    const bf16* kp1 = qkv + KOFF + g * DH + (size_t)krow1 * NC + (((lane & 15) ^ (krow1 & 7)) * 8);
    const int vdd0 = wave * 32 + (lane >> 3);           // chunk i=0 d-row
    const bf16* vp0 = vt + (size_t)(g * DH + vdd0) * SEQ + (((lane & 7) ^ ((lane >> 3) & 7)) * 8);

    // Q -> registers (B operand): lane n=l31 -> q-row; k = lh*8 + s*16 + j
    bf16x8 qf[8];
    {
        const int qrow = r_base + (l31 & 15);
        const int head = g * 4 + hp * 2 + (l31 >> 4);
        const bf16* qp = qkv + (size_t)qrow * NC + head * DH + lh * 8;
        #pragma unroll
        for (int s = 0; s < 8; ++s)
            qf[s] = *(const bf16x8*)(qp + s * 16);
    }

    f32x16 o_acc[4] = {};
    float lsum = 0.0f;

    for (int kt = 0; kt <= ktmax; ++kt) {
        __syncthreads();   // all waves done reading Ks/Vs of prev iter
        load_lds16(kp0,                        Ks + (wave * 4 + 0) * 512);
        load_lds16(kp1,                        Ks + (wave * 4 + 1) * 512);
        load_lds16(kp0 + (size_t)8 * NC,       Ks + (wave * 4 + 2) * 512);
        load_lds16(kp1 + (size_t)8 * NC,       Ks + (wave * 4 + 3) * 512);
        load_lds16(vp0,                        Vs + (wave * 4 + 0) * 512);
        load_lds16(vp0 + (size_t)8 * SEQ,      Vs + (wave * 4 + 1) * 512);
        load_lds16(vp0 + (size_t)16 * SEQ,     Vs + (wave * 4 + 2) * 512);
        load_lds16(vp0 + (size_t)24 * SEQ,     Vs + (wave * 4 + 3) * 512);
        __syncthreads();   // compiler drains vmcnt(0) before barrier
        kp0 += (size_t)64 * NC; kp1 += (size_t)64 * NC; vp0 += 64;

        const int key_min = kt * 64 + kh * 32;
        if (key_min <= r_base + 15) {   // some key unmasked for this chunk
            // S^T = K Q^T, split into two independent 4-chains (halve dep latency)
            f32x16 sa = {}, sb = {};
            __builtin_amdgcn_s_setprio(1);
            #pragma unroll
            for (int s = 0; s < 4; ++s) {
                bf16x8 kb0 = *(const bf16x8*)&Ks[(kh * 32 + l31) * 128 + (((lh + 4 * s) ^ rsw) * 8)];
                sa = __builtin_amdgcn_mfma_f32_32x32x16_bf16(kb0, qf[2 * s], sa, 0, 0, 0);
                bf16x8 kb1 = *(const bf16x8*)&Ks[(kh * 32 + l31) * 128 + (((lh + 4 * s + 2) ^ rsw) * 8)];
                sb = __builtin_amdgcn_mfma_f32_32x32x16_bf16(kb1, qf[2 * s + 1], sb, 0, 0, 0);
            }
            __builtin_amdgcn_s_setprio(0);
            f32x16 sacc = sa + sb;

            const bool needmask = (key_min + 31 > r_base);
            const int qrow = r_base + (l31 & 15);
            float e[16];
            if (needmask) {   // diagonal tile only (~1 of ~33 iters)
                #pragma unroll
                for (int rg = 0; rg < 16; ++rg) {
                    const int keyg = key_min + (rg & 3) + 8 * (rg >> 2) + 4 * lh;
                    float sv = sacc[rg];
                    if (keyg > qrow) sv = -INFINITY;
                    e[rg] = exp2f(sv);
                }
            } else {
                #pragma unroll
                for (int rg = 0; rg < 16; ++rg)
                    e[rg] = exp2f(sacc[rg]);
            }
            {
                float t0 = (e[0] + e[1]) + (e[2] + e[3]);
                float t1 = (e[4] + e[5]) + (e[6] + e[7]);
                float t2 = (e[8] + e[9]) + (e[10] + e[11]);
                float t3 = (e[12] + e[13]) + (e[14] + e[15]);
                lsum += (t0 + t1) + (t2 + t3);
            }

            // P -> A fragments in-register (T12)
            bf16x8 pa[2];
            #pragma unroll
            for (int s2 = 0; s2 < 2; ++s2) {
                uint32_t wA0, wA1, wB0, wB1;
                asm("v_cvt_pk_bf16_f32 %0, %1, %2" : "=v"(wA0) : "v"(e[8*s2+0]), "v"(e[8*s2+1]));
                asm("v_cvt_pk_bf16_f32 %0, %1, %2" : "=v"(wA1) : "v"(e[8*s2+2]), "v"(e[8*s2+3]));
                asm("v_cvt_pk_bf16_f32 %0, %1, %2" : "=v"(wB0) : "v"(e[8*s2+4]), "v"(e[8*s2+5]));
                asm("v_cvt_pk_bf16_f32 %0, %1, %2" : "=v"(wB1) : "v"(e[8*s2+6]), "v"(e[8*s2+7]));
                asm volatile("v_permlane32_swap_b32 %0, %1" : "+v"(wA0), "+v"(wB0));
                asm volatile("v_permlane32_swap_b32 %0, %1" : "+v"(wA1), "+v"(wB1));
                union { uint32_t u[4]; bf16x8 v; } cvt;
                cvt.u[0] = wA0; cvt.u[1] = wA1; cvt.u[2] = wB0; cvt.u[3] = wB1;
                pa[s2] = cvt.v;
            }

            // PV: nt innermost -> consecutive MFMAs hit independent accumulators
            __builtin_amdgcn_s_setprio(1);
            #pragma unroll
            for (int s2 = 0; s2 < 2; ++s2) {
                #pragma unroll
                for (int nt = 0; nt < 4; ++nt) {
                    bf16x8 vb = *(const bf16x8*)&Vs[(nt * 32 + l31) * 64 + (((kh * 4 + lh + 2 * s2) ^ rsw) * 8)];
                    o_acc[nt] = __builtin_amdgcn_mfma_f32_32x32x16_bf16(pa[s2], vb, o_acc[nt], 0, 0, 0);
                }
            }
            __builtin_amdgcn_s_setprio(0);
        }
    }

    // merge lh halves of l in-register
    float la = lsum, lb = lsum;
    asm volatile("v_permlane32_swap_b32 %0, %1" : "+v"(la), "+v"(lb));
    const float l_tot = la + lb;   // full 32-key-half sum for q-row l31

    // ---- merge key-half partials (linear: no max alignment needed) ----
    __syncthreads();               // all compute done; Ks/Vs region free for ob
    if (lh == 0) lml[wave * 32 + l31] = l_tot;
    if (kh == 1) {
        #pragma unroll
        for (int nt = 0; nt < 4; ++nt)
            #pragma unroll
            for (int rg = 0; rg < 16; ++rg) {
                const int m = (rg & 3) + 8 * (rg >> 2) + 4 * lh;
                ob[(ch * 32 + m) * 128 + nt * 32 + l31] = o_acc[nt][rg];
            }
    }
    __syncthreads();
    if (kh == 0) {
        float invl[16];
        #pragma unroll
        for (int rg = 0; rg < 16; ++rg) {
            const int m = (rg & 3) + 8 * (rg >> 2) + 4 * lh;
            invl[rg] = 1.0f / (lml[wave * 32 + m] + lml[(wave + 1) * 32 + m]);
        }
        #pragma unroll
        for (int nt = 0; nt < 4; ++nt)
            #pragma unroll
            for (int rg = 0; rg < 16; ++rg) {
                const int m = (rg & 3) + 8 * (rg >> 2) + 4 * lh;
                float oo = o_acc[nt][rg] + ob[(ch * 32 + m) * 128 + nt * 32 + l31];
                const int row = r_base + (m & 15);
                const int col = (g * 4 + hp * 2 + (m >> 4)) * DH + nt * 32 + l31;
                z[(size_t)row * DM + col] = f2bf(oo * invl[rg]);
            }
    }
}

// ---------------- launch ----------------
extern "C" void kernel_launch(void* const* d_in, const int* in_sizes, int n_in,
                              void* d_out, int out_size, void* d_ws, size_t ws_size,
                              hipStream_t stream) {
    const float* x  = (const float*)d_in[0];
    const float* WQ = (const float*)d_in[1];
    const float* WK = (const float*)d_in[2];
    const float* WV = (const float*)d_in[3];
    const float* WO = (const float*)d_in[4];
    const float* bQ = (const float*)d_in[5];
    const float* bK = (const float*)d_in[6];
    const float* bV = (const float*)d_in[7];
    const float* bO = (const float*)d_in[8];
    float* out = (float*)d_out;

    char* ws = (char*)d_ws;
    bf16*  wt_cat = (bf16*)(ws);                  // 12,582,912
    bf16*  wt_o   = (bf16*)(ws + 12582912);       //  8,388,608
    float* bias_c = (float*)(ws + 20971520);      //  16,384 (padded)
    bf16*  qkv    = (bf16*)(ws + 20987904);       // 25,165,824
    bf16*  vt     = (bf16*)(ws + 46153728);       //  4,194,304
    bf16*  z      = (bf16*)(ws + 50348032);       // 16,777,216
    bf16*  xb     = (bf16*)(ws + 67125248);       // 16,777,216
    float2* sct   = (float2*)vt;                  // 2,097,152: vt region dead until
                                                  // vtrans, sct dead after gemm1

    xconv    <<<8192, 256, 0, stream>>>(x, xb);
    prep_wqkv<<<dim3(32, 48), 256, 0, stream>>>(WQ, WK, WV, wt_cat);
    prep_wo  <<<dim3(32, 32), 256, 0, stream>>>(WO, wt_o);
    prep_bias<<<12, 256, 0, stream>>>(bQ, bK, bV, bias_c);
    sctab    <<<1024, 256, 0, stream>>>(sct);
    gemm_bt<bf16, 1> <<<dim3(24, 32), 256, 0, stream>>>(xb, wt_cat, bias_c, qkv, NC, sct);
    vtrans   <<<512, 256, 0, stream>>>(qkv, vt);
    flash    <<<1024, 256, 0, stream>>>(qkv, vt, z);
    gemm_bt<float, 0><<<dim3(16, 32), 256, 0, stream>>>(z, wt_o, bO, out, DM, nullptr);
}

// Round 11
// 342.043 us; speedup vs baseline: 1.0723x; 1.0437x over previous
//
#include <hip/hip_runtime.h>
#include <hip/hip_bf16.h>
#include <cstdint>
#include <cstddef>

#define SEQ    4096
#define DM     2048
#define DH     128
#define NH     16
#define NKV    4
#define NC     3072          // qkv output columns: 2048 q | 512 k | 512 v
#define KOFF   2048
#define VOFF   2560
// 1/sqrt(128) * log2(e): q pre-scale so softmax runs in base-2 (exp2)
#define Q_SCALE 0.12751730f

using bf16 = __hip_bfloat16;
typedef __bf16 bf16x8 __attribute__((ext_vector_type(8)));
typedef float f32x4 __attribute__((ext_vector_type(4)));
typedef float f32x16 __attribute__((ext_vector_type(16)));

static __device__ inline float bf2f(bf16 x) { return __bfloat162float(x); }
static __device__ inline bf16 f2bf(float x) { return __float2bfloat16(x); }

// async global->LDS, 16B per lane. LDS dest = wave-uniform base + lane*16.
static __device__ inline void load_lds16(const bf16* g, bf16* l) {
    __builtin_amdgcn_global_load_lds(
        (const __attribute__((address_space(1))) uint32_t*)g,
        (__attribute__((address_space(3))) uint32_t*)l, 16, 0, 0);
}

// ---------------- x: f32 -> bf16 ----------------
__global__ void xconv(const float* __restrict__ in, bf16* __restrict__ out) {
    int i = blockIdx.x * 256 + threadIdx.x;   // one float4 per thread
    float4 v = ((const float4*)in)[i];
    bf16 a = f2bf(v.x), b = f2bf(v.y), c = f2bf(v.z), d = f2bf(v.w);
    ushort4 u;
    u.x = *(unsigned short*)&a; u.y = *(unsigned short*)&b;
    u.z = *(unsigned short*)&c; u.w = *(unsigned short*)&d;
    ((ushort4*)out)[i] = u;
}

// ---------------- prep: LDS-tiled weight transposes (f32 -> bf16) ----------------
__global__ void prep_wqkv(const float* __restrict__ WQ, const float* __restrict__ WK,
                          const float* __restrict__ WV, bf16* __restrict__ wt) {
    __shared__ float tl[64][65];
    const int t = threadIdx.x;
    const int m0 = (int)blockIdx.x * 64;            // m-tile
    const int head = (int)blockIdx.y >> 1;          // 0..23 = Q0..15,K0..3,V0..3
    const int h0 = ((int)blockIdx.y & 1) * 64;      // h-tile
    const float* src = (head < 16) ? WQ + (size_t)head * DM * DH
                     : (head < 20) ? WK + (size_t)(head - 16) * DM * DH
                                   : WV + (size_t)(head - 20) * DM * DH;
    {
        const int r = t >> 2, c = (t & 3) * 16;
        const float* p = src + (size_t)(m0 + r) * DH + h0 + c;
        #pragma unroll
        for (int kk = 0; kk < 4; ++kk) {
            float4 v = *(const float4*)(p + kk * 4);
            tl[r][c + kk * 4 + 0] = v.x; tl[r][c + kk * 4 + 1] = v.y;
            tl[r][c + kk * 4 + 2] = v.z; tl[r][c + kk * 4 + 3] = v.w;
        }
    }
    __syncthreads();
    {
        const int hh = t >> 2, ms = (t & 3) * 16;
        const int j = head * 128 + h0 + hh;         // concat row (Q|K|V)
        bf16 tmp[16];
        #pragma unroll
        for (int i = 0; i < 16; ++i) tmp[i] = f2bf(tl[ms + i][hh]);
        bf16* q = wt + (size_t)j * DM + m0 + ms;
        *(bf16x8*)q       = *(bf16x8*)&tmp[0];
        *(bf16x8*)(q + 8) = *(bf16x8*)&tmp[8];
    }
}

__global__ void prep_wo(const float* __restrict__ WO, bf16* __restrict__ wt) {
    __shared__ float tl[64][65];
    const int t = threadIdx.x;
    const int m0 = (int)blockIdx.x * 64;   // WO row tile ((n,h) dim)
    const int j0 = (int)blockIdx.y * 64;   // WO col tile (d_model)
    {
        const int r = t >> 2, c = (t & 3) * 16;
        const float* p = WO + (size_t)(m0 + r) * DM + j0 + c;
        #pragma unroll
        for (int kk = 0; kk < 4; ++kk) {
            float4 v = *(const float4*)(p + kk * 4);
            tl[r][c + kk * 4 + 0] = v.x; tl[r][c + kk * 4 + 1] = v.y;
            tl[r][c + kk * 4 + 2] = v.z; tl[r][c + kk * 4 + 3] = v.w;
        }
    }
    __syncthreads();
    {
        const int hh = t >> 2, ms = (t & 3) * 16;
        bf16 tmp[16];
        #pragma unroll
        for (int i = 0; i < 16; ++i) tmp[i] = f2bf(tl[ms + i][hh]);
        bf16* q = wt + (size_t)(j0 + hh) * DM + m0 + ms;
        *(bf16x8*)q       = *(bf16x8*)&tmp[0];
        *(bf16x8*)(q + 8) = *(bf16x8*)&tmp[8];
    }
}

// ---------------- rotary cos/sin table + bias concat (merged) ----------------
__global__ void sctab(float2* __restrict__ tab,
                      const float* __restrict__ bQ, const float* __restrict__ bK,
                      const float* __restrict__ bV, float* __restrict__ bias) {
    int idx = blockIdx.x * 256 + threadIdx.x;   // 0..262143
    int s = idx >> 6, i = idx & 63;
    float inv_freq = __expf(-(float)i * 0.14391156831212788f);
    float ang = (float)s * inv_freq;
    float2 cs;
    cs.x = cosf(ang);
    cs.y = sinf(ang);
    tab[idx] = cs;
    if (idx < NC)
        bias[idx] = (idx < KOFF) ? bQ[idx] : (idx < VOFF ? bK[idx - KOFF] : bV[idx - VOFF]);
}

// ---------------- GEMM: C[M][N] = A[M][2048] * Bt[N][2048]^T + bias ----------------
// 2-phase 128x128 (768/512 blocks = full CU coverage; r9: 256-tile underfills).
// ROT=1: fused rotary epilogue for q/k cols; V cols (n0>=VOFF) write TRANSPOSED
// into vtq[vcol][s] via an LDS round-trip (As/Bs space is dead post-loop) --
// replaces the standalone vtrans kernel.
#define BM 128
#define BN 128
#define BK 64
#define VTL 132   // vtile row stride (elems)

template <typename OutT, int ROT>
__global__ __launch_bounds__(256)
void gemm_bt(const bf16* __restrict__ A, const bf16* __restrict__ Bt,
             const float* __restrict__ bias, OutT* __restrict__ C, int N,
             const float2* __restrict__ tab, bf16* __restrict__ vtq) {
    __shared__ __align__(16) char smemraw[33792];  // As|Bs (32KB) / vtile [128][132]
    bf16* As = (bf16*)smemraw;
    bf16* Bs = (bf16*)(smemraw + 16384);
    const int tid = threadIdx.x;
    const int wave = tid >> 6, lane = tid & 63;
    const int quad = lane >> 4, l15 = lane & 15;
    const int wm = (wave >> 1) * 64, wn = (wave & 1) * 64;
    const int m0 = blockIdx.y * BM, n0 = blockIdx.x * BN;

    f32x4 acc[4][4] = {};

    const bf16* gsrc = (wave < 2)
        ? A  + (size_t)(m0 + (wave & 1) * 64) * DM
        : Bt + (size_t)(n0 + (wave & 1) * 64) * DM;
    bf16* lbase = (wave < 2 ? As : Bs) + (wave & 1) * 64 * BK;
    const int lrow = lane >> 3;                          // 0..7
    const int gslot = (lane & 7) ^ lrow;                 // swizzled source slot
    const bf16* gp = gsrc + (size_t)lrow * DM + gslot * 8;

    const int rsw = l15 & 7;

    for (int k0 = 0; k0 < DM; k0 += BK) {
        __syncthreads();
        #pragma unroll
        for (int cc = 0; cc < 8; ++cc)
            load_lds16(gp + (size_t)cc * 8 * DM + k0, lbase + cc * 8 * BK);
        __syncthreads();

        #pragma unroll
        for (int ks = 0; ks < 2; ++ks) {
            bf16x8 af[4], bfr[4];
            #pragma unroll
            for (int i = 0; i < 4; ++i)
                af[i] = *(const bf16x8*)&As[(wm + i * 16 + l15) * BK + (((ks * 4 + quad) ^ rsw) * 8)];
            #pragma unroll
            for (int j = 0; j < 4; ++j)
                bfr[j] = *(const bf16x8*)&Bs[(wn + j * 16 + l15) * BK + (((ks * 4 + quad) ^ rsw) * 8)];
            #pragma unroll
            for (int i = 0; i < 4; ++i)
                #pragma unroll
                for (int j = 0; j < 4; ++j)
                    acc[i][j] = __builtin_amdgcn_mfma_f32_16x16x32_bf16(af[i], bfr[j], acc[i][j], 0, 0, 0);
        }
    }

    if (ROT && n0 >= VOFF) {
        // ---- V tile: write transposed to vtq[vcol][s] via LDS ----
        __syncthreads();                       // all waves done with As/Bs
        bf16* vtile = (bf16*)smemraw;          // [128 cols][VTL]
        #pragma unroll
        for (int i = 0; i < 4; ++i) {
            const int rl0 = wm + i * 16 + quad * 4;
            #pragma unroll
            for (int j = 0; j < 4; ++j) {
                const int cl = wn + j * 16 + l15;
                const float bv = bias[n0 + cl];
                ushort4 w;
                bf16 h;
                h = f2bf(acc[i][j][0] + bv); w.x = *(unsigned short*)&h;
                h = f2bf(acc[i][j][1] + bv); w.y = *(unsigned short*)&h;
                h = f2bf(acc[i][j][2] + bv); w.z = *(unsigned short*)&h;
                h = f2bf(acc[i][j][3] + bv); w.w = *(unsigned short*)&h;
                *(ushort4*)&vtile[cl * VTL + rl0] = w;
            }
        }
        __syncthreads();
        // coalesced-ish store: 8 lanes cover 128B of one col per pass
        #pragma unroll
        for (int p = 0; p < 4; ++p) {
            const int c = p * 32 + (tid >> 3);
            const int s = (tid & 7) * 16;
            bf16* dst = vtq + (size_t)(n0 - VOFF + c) * SEQ + m0 + s;
            const bf16* srcl = vtile + c * VTL + s;
            *(bf16x8*)dst       = *(const bf16x8*)srcl;
            *(bf16x8*)(dst + 8) = *(const bf16x8*)(srcl + 8);
        }
        return;
    }

    const bool doRot = ROT && (n0 < VOFF);
    const float scl = (n0 < KOFF) ? Q_SCALE : 1.0f;

    #pragma unroll
    for (int i = 0; i < 4; ++i) {
        int row = m0 + wm + i * 16 + quad * 4;
        #pragma unroll
        for (int j = 0; j < 4; ++j) {
            int col = n0 + wn + j * 16 + l15;
            float bv = bias[col];
            if (ROT && doRot) {
                const int ii = (col >> 1) & 63;
                const bool odd = col & 1;
                #pragma unroll
                for (int r = 0; r < 4; ++r) {
                    float v = acc[i][j][r] + bv;
                    float pv = __shfl_xor(v, 1);
                    float2 cs = tab[((row + r) << 6) + ii];
                    float o = odd ? (pv * cs.y + v * cs.x) : (v * cs.x - pv * cs.y);
                    C[(size_t)(row + r) * N + col] = (OutT)f2bf(o * scl);
                }
            } else {
                #pragma unroll
                for (int r = 0; r < 4; ++r) {
                    float val = acc[i][j][r] + bv;
                    if constexpr (sizeof(OutT) == 2)
                        C[(size_t)(row + r) * N + col] = f2bf(val);
                    else
                        C[(size_t)(row + r) * N + col] = val;
                }
            }
        }
    }
}

// ---------------- flash attention v9 (frozen from r8: 110.2 us) ----------------
// 1024 blocks x 256 thr; block = (qt, g, hp), biggest-qt-first (LPT backfill).
// 4 waves = 2 ch x 2 kh. K/V via global_load_lds, XOR involution swizzle,
// swapped QK^T + in-reg P (T12), (256,3) cap = 3 blocks/CU (occupancy > spill).
__global__ __launch_bounds__(256, 3)
void flash(const bf16* __restrict__ qkv, const bf16* __restrict__ vt,
           bf16* __restrict__ z) {
    __shared__ char smem[33280];
    bf16*  Ks  = (bf16*)smem;                    // [64][128]  = 16384 B (swizzled)
    bf16*  Vs  = (bf16*)(smem + 16384);          // [128][64]  = 16384 B (swizzled)
    float* lml = (float*)(smem + 32768);         // 4 x 32     =   512 B
    float* ob  = (float*)smem;                   // merge reuse: 2*32*128 f32 = 32768 B

    const int tid = threadIdx.x;
    const int wave = tid >> 6, lane = tid & 63;
    const int l31 = lane & 31, lh = lane >> 5;
    const int ch = wave >> 1;         // row chunk (16 rows)
    const int kh = wave & 1;          // key half (32 keys)
    const int bx = blockIdx.x;
    const int qt = 127 - (bx >> 3);   // biggest first
    const int g = (bx >> 1) & 3;      // KV group
    const int hp = bx & 1;            // head pair within group
    const int r_base = qt * 32 + ch * 16;
    const int ktmax = qt >> 1;
    const int rsw = l31 & 7;          // read-side XOR (row&7 for both QK and PV reads)

    // staging pointers (3 total; folding: krow&7 repeats every 8 rows, vdd&7 is
    // chunk-independent)
    const int krow0 = wave * 16 + (lane >> 4);          // chunk i=0 row
    const int krow1 = krow0 + 4;                        // chunk i=1 row
    const bf16* kp0 = qkv + KOFF + g * DH + (size_t)krow0 * NC + (((lane & 15) ^ (krow0 & 7)) * 8);
    const bf16* kp1 = qkv + KOFF + g * DH + (size_t)krow1 * NC + (((lane & 15) ^ (krow1 & 7)) * 8);
    const int vdd0 = wave * 32 + (lane >> 3);           // chunk i=0 d-row
    const bf16* vp0 = vt + (size_t)(g * DH + vdd0) * SEQ + (((lane & 7) ^ ((lane >> 3) & 7)) * 8);

    // Q -> registers (B operand): lane n=l31 -> q-row; k = lh*8 + s*16 + j
    bf16x8 qf[8];
    {
        const int qrow = r_base + (l31 & 15);
        const int head = g * 4 + hp * 2 + (l31 >> 4);
        const bf16* qp = qkv + (size_t)qrow * NC + head * DH + lh * 8;
        #pragma unroll
        for (int s = 0; s < 8; ++s)
            qf[s] = *(const bf16x8*)(qp + s * 16);
    }

    f32x16 o_acc[4] = {};
    float lsum = 0.0f;

    for (int kt = 0; kt <= ktmax; ++kt) {
        __syncthreads();   // all waves done reading Ks/Vs of prev iter
        load_lds16(kp0,                        Ks + (wave * 4 + 0) * 512);
        load_lds16(kp1,                        Ks + (wave * 4 + 1) * 512);
        load_lds16(kp0 + (size_t)8 * NC,       Ks + (wave * 4 + 2) * 512);
        load_lds16(kp1 + (size_t)8 * NC,       Ks + (wave * 4 + 3) * 512);
        load_lds16(vp0,                        Vs + (wave * 4 + 0) * 512);
        load_lds16(vp0 + (size_t)8 * SEQ,      Vs + (wave * 4 + 1) * 512);
        load_lds16(vp0 + (size_t)16 * SEQ,     Vs + (wave * 4 + 2) * 512);
        load_lds16(vp0 + (size_t)24 * SEQ,     Vs + (wave * 4 + 3) * 512);
        __syncthreads();   // compiler drains vmcnt(0) before barrier
        kp0 += (size_t)64 * NC; kp1 += (size_t)64 * NC; vp0 += 64;

        const int key_min = kt * 64 + kh * 32;
        if (key_min <= r_base + 15) {   // some key unmasked for this chunk
            // S^T = K Q^T : lane l31 = q-row, regs = 16 keys
            f32x16 sacc = {};
            __builtin_amdgcn_s_setprio(1);
            #pragma unroll
            for (int s = 0; s < 8; ++s) {
                bf16x8 kb = *(const bf16x8*)&Ks[(kh * 32 + l31) * 128 + (((lh + 2 * s) ^ rsw) * 8)];
                sacc = __builtin_amdgcn_mfma_f32_32x32x16_bf16(kb, qf[s], sacc, 0, 0, 0);
            }
            __builtin_amdgcn_s_setprio(0);

            const bool needmask = (key_min + 31 > r_base);
            const int qrow = r_base + (l31 & 15);
            float e[16];
            if (needmask) {   // diagonal tile only (~1 of ~33 iters)
                #pragma unroll
                for (int rg = 0; rg < 16; ++rg) {
                    const int keyg = key_min + (rg & 3) + 8 * (rg >> 2) + 4 * lh;
                    float sv = sacc[rg];
                    if (keyg > qrow) sv = -INFINITY;
                    e[rg] = exp2f(sv);
                }
            } else {
                #pragma unroll
                for (int rg = 0; rg < 16; ++rg)
                    e[rg] = exp2f(sacc[rg]);
            }
            {
                float t0 = (e[0] + e[1]) + (e[2] + e[3]);
                float t1 = (e[4] + e[5]) + (e[6] + e[7]);
                float t2 = (e[8] + e[9]) + (e[10] + e[11]);
                float t3 = (e[12] + e[13]) + (e[14] + e[15]);
                lsum += (t0 + t1) + (t2 + t3);
            }

            // P -> A fragments in-register (T12)
            bf16x8 pa[2];
            #pragma unroll
            for (int s2 = 0; s2 < 2; ++s2) {
                uint32_t wA0, wA1, wB0, wB1;
                asm("v_cvt_pk_bf16_f32 %0, %1, %2" : "=v"(wA0) : "v"(e[8*s2+0]), "v"(e[8*s2+1]));
                asm("v_cvt_pk_bf16_f32 %0, %1, %2" : "=v"(wA1) : "v"(e[8*s2+2]), "v"(e[8*s2+3]));
                asm("v_cvt_pk_bf16_f32 %0, %1, %2" : "=v"(wB0) : "v"(e[8*s2+4]), "v"(e[8*s2+5]));
                asm("v_cvt_pk_bf16_f32 %0, %1, %2" : "=v"(wB1) : "v"(e[8*s2+6]), "v"(e[8*s2+7]));
                asm volatile("v_permlane32_swap_b32 %0, %1" : "+v"(wA0), "+v"(wB0));
                asm volatile("v_permlane32_swap_b32 %0, %1" : "+v"(wA1), "+v"(wB1));
                union { uint32_t u[4]; bf16x8 v; } cvt;
                cvt.u[0] = wA0; cvt.u[1] = wA1; cvt.u[2] = wB0; cvt.u[3] = wB1;
                pa[s2] = cvt.v;
            }

            // PV: A = P fragments (in-reg), B = V^T fragments from LDS
            __builtin_amdgcn_s_setprio(1);
            #pragma unroll
            for (int nt = 0; nt < 4; ++nt) {
                #pragma unroll
                for (int s2 = 0; s2 < 2; ++s2) {
                    bf16x8 vb = *(const bf16x8*)&Vs[(nt * 32 + l31) * 64 + (((kh * 4 + lh + 2 * s2) ^ rsw) * 8)];
                    o_acc[nt] = __builtin_amdgcn_mfma_f32_32x32x16_bf16(pa[s2], vb, o_acc[nt], 0, 0, 0);
                }
            }
            __builtin_amdgcn_s_setprio(0);
        }
    }

    // merge lh halves of l in-register
    float la = lsum, lb = lsum;
    asm volatile("v_permlane32_swap_b32 %0, %1" : "+v"(la), "+v"(lb));
    const float l_tot = la + lb;   // full 32-key-half sum for q-row l31

    // ---- merge key-half partials (linear: no max alignment needed) ----
    __syncthreads();               // all compute done; Ks/Vs region free for ob
    if (lh == 0) lml[wave * 32 + l31] = l_tot;
    if (kh == 1) {
        #pragma unroll
        for (int nt = 0; nt < 4; ++nt)
            #pragma unroll
            for (int rg = 0; rg < 16; ++rg) {
                const int m = (rg & 3) + 8 * (rg >> 2) + 4 * lh;
                ob[(ch * 32 + m) * 128 + nt * 32 + l31] = o_acc[nt][rg];
            }
    }
    __syncthreads();
    if (kh == 0) {
        float invl[16];
        #pragma unroll
        for (int rg = 0; rg < 16; ++rg) {
            const int m = (rg & 3) + 8 * (rg >> 2) + 4 * lh;
            invl[rg] = 1.0f / (lml[wave * 32 + m] + lml[(wave + 1) * 32 + m]);
        }
        #pragma unroll
        for (int nt = 0; nt < 4; ++nt)
            #pragma unroll
            for (int rg = 0; rg < 16; ++rg) {
                const int m = (rg & 3) + 8 * (rg >> 2) + 4 * lh;
                float oo = o_acc[nt][rg] + ob[(ch * 32 + m) * 128 + nt * 32 + l31];
                const int row = r_base + (m & 15);
                const int col = (g * 4 + hp * 2 + (m >> 4)) * DH + nt * 32 + l31;
                z[(size_t)row * DM + col] = f2bf(oo * invl[rg]);
            }
    }
}

// ---------------- launch ----------------
extern "C" void kernel_launch(void* const* d_in, const int* in_sizes, int n_in,
                              void* d_out, int out_size, void* d_ws, size_t ws_size,
                              hipStream_t stream) {
    const float* x  = (const float*)d_in[0];
    const float* WQ = (const float*)d_in[1];
    const float* WK = (const float*)d_in[2];
    const float* WV = (const float*)d_in[3];
    const float* WO = (const float*)d_in[4];
    const float* bQ = (const float*)d_in[5];
    const float* bK = (const float*)d_in[6];
    const float* bV = (const float*)d_in[7];
    const float* bO = (const float*)d_in[8];
    float* out = (float*)d_out;

    char* ws = (char*)d_ws;
    bf16*  wt_cat = (bf16*)(ws);                  // 12,582,912
    bf16*  wt_o   = (bf16*)(ws + 12582912);       //  8,388,608
    float* bias_c = (float*)(ws + 20971520);      //  16,384 (padded)
    bf16*  qkv    = (bf16*)(ws + 20987904);       // 25,165,824
    bf16*  vt     = (bf16*)(ws + 46153728);       //  4,194,304 (written by gemm1 V-epilogue)
    bf16*  z      = (bf16*)(ws + 50348032);       // 16,777,216
    bf16*  xb     = (bf16*)(ws + 67125248);       // 16,777,216
    float2* sct   = (float2*)z;                   // 2,097,152: z region dead until
                                                  // flash; sct dead after gemm1

    xconv    <<<8192, 256, 0, stream>>>(x, xb);
    prep_wqkv<<<dim3(32, 48), 256, 0, stream>>>(WQ, WK, WV, wt_cat);
    prep_wo  <<<dim3(32, 32), 256, 0, stream>>>(WO, wt_o);
    sctab    <<<1024, 256, 0, stream>>>(sct, bQ, bK, bV, bias_c);
    gemm_bt<bf16, 1> <<<dim3(24, 32), 256, 0, stream>>>(xb, wt_cat, bias_c, qkv, NC, sct, vt);
    flash    <<<1024, 256, 0, stream>>>(qkv, vt, z);
    gemm_bt<float, 0><<<dim3(16, 32), 256, 0, stream>>>(z, wt_o, bO, out, DM, nullptr, nullptr);
}

// Round 12
// 325.582 us; speedup vs baseline: 1.1266x; 1.0506x over previous
//
#include <hip/hip_runtime.h>
#include <hip/hip_bf16.h>
#include <cstdint>
#include <cstddef>

#define SEQ    4096
#define DM     2048
#define DH     128
#define NH     16
#define NKV    4
#define NC     3072          // qkv output columns: 2048 q | 512 k | 512 v
#define KOFF   2048
#define VOFF   2560
// 1/sqrt(128) * log2(e): q pre-scale so softmax runs in base-2 (exp2)
#define Q_SCALE 0.12751730f

using bf16 = __hip_bfloat16;
typedef __bf16 bf16x8 __attribute__((ext_vector_type(8)));
typedef float f32x4 __attribute__((ext_vector_type(4)));
typedef float f32x16 __attribute__((ext_vector_type(16)));

static __device__ inline float bf2f(bf16 x) { return __bfloat162float(x); }
static __device__ inline bf16 f2bf(float x) { return __float2bfloat16(x); }

// async global->LDS, 16B per lane. LDS dest = wave-uniform base + lane*16.
static __device__ inline void load_lds16(const bf16* g, bf16* l) {
    __builtin_amdgcn_global_load_lds(
        (const __attribute__((address_space(1))) uint32_t*)g,
        (__attribute__((address_space(3))) uint32_t*)l, 16, 0, 0);
}

// ---------------- x: f32 -> bf16 ----------------
__global__ void xconv(const float* __restrict__ in, bf16* __restrict__ out) {
    int i = blockIdx.x * 256 + threadIdx.x;   // one float4 per thread
    float4 v = ((const float4*)in)[i];
    bf16 a = f2bf(v.x), b = f2bf(v.y), c = f2bf(v.z), d = f2bf(v.w);
    ushort4 u;
    u.x = *(unsigned short*)&a; u.y = *(unsigned short*)&b;
    u.z = *(unsigned short*)&c; u.w = *(unsigned short*)&d;
    ((ushort4*)out)[i] = u;
}

// ---------------- prep: LDS-tiled weight transposes (f32 -> bf16) ----------------
__global__ void prep_wqkv(const float* __restrict__ WQ, const float* __restrict__ WK,
                          const float* __restrict__ WV, bf16* __restrict__ wt) {
    __shared__ float tl[64][65];
    const int t = threadIdx.x;
    const int m0 = (int)blockIdx.x * 64;            // m-tile
    const int head = (int)blockIdx.y >> 1;          // 0..23 = Q0..15,K0..3,V0..3
    const int h0 = ((int)blockIdx.y & 1) * 64;      // h-tile
    const float* src = (head < 16) ? WQ + (size_t)head * DM * DH
                     : (head < 20) ? WK + (size_t)(head - 16) * DM * DH
                                   : WV + (size_t)(head - 20) * DM * DH;
    {
        const int r = t >> 2, c = (t & 3) * 16;
        const float* p = src + (size_t)(m0 + r) * DH + h0 + c;
        #pragma unroll
        for (int kk = 0; kk < 4; ++kk) {
            float4 v = *(const float4*)(p + kk * 4);
            tl[r][c + kk * 4 + 0] = v.x; tl[r][c + kk * 4 + 1] = v.y;
            tl[r][c + kk * 4 + 2] = v.z; tl[r][c + kk * 4 + 3] = v.w;
        }
    }
    __syncthreads();
    {
        const int hh = t >> 2, ms = (t & 3) * 16;
        const int j = head * 128 + h0 + hh;         // concat row (Q|K|V)
        bf16 tmp[16];
        #pragma unroll
        for (int i = 0; i < 16; ++i) tmp[i] = f2bf(tl[ms + i][hh]);
        bf16* q = wt + (size_t)j * DM + m0 + ms;
        *(bf16x8*)q       = *(bf16x8*)&tmp[0];
        *(bf16x8*)(q + 8) = *(bf16x8*)&tmp[8];
    }
}

__global__ void prep_wo(const float* __restrict__ WO, bf16* __restrict__ wt) {
    __shared__ float tl[64][65];
    const int t = threadIdx.x;
    const int m0 = (int)blockIdx.x * 64;   // WO row tile ((n,h) dim)
    const int j0 = (int)blockIdx.y * 64;   // WO col tile (d_model)
    {
        const int r = t >> 2, c = (t & 3) * 16;
        const float* p = WO + (size_t)(m0 + r) * DM + j0 + c;
        #pragma unroll
        for (int kk = 0; kk < 4; ++kk) {
            float4 v = *(const float4*)(p + kk * 4);
            tl[r][c + kk * 4 + 0] = v.x; tl[r][c + kk * 4 + 1] = v.y;
            tl[r][c + kk * 4 + 2] = v.z; tl[r][c + kk * 4 + 3] = v.w;
        }
    }
    __syncthreads();
    {
        const int hh = t >> 2, ms = (t & 3) * 16;
        bf16 tmp[16];
        #pragma unroll
        for (int i = 0; i < 16; ++i) tmp[i] = f2bf(tl[ms + i][hh]);
        bf16* q = wt + (size_t)(j0 + hh) * DM + m0 + ms;
        *(bf16x8*)q       = *(bf16x8*)&tmp[0];
        *(bf16x8*)(q + 8) = *(bf16x8*)&tmp[8];
    }
}

// ---------------- rotary cos/sin table + bias concat (merged) ----------------
__global__ void sctab(float2* __restrict__ tab,
                      const float* __restrict__ bQ, const float* __restrict__ bK,
                      const float* __restrict__ bV, float* __restrict__ bias) {
    int idx = blockIdx.x * 256 + threadIdx.x;   // 0..262143
    int s = idx >> 6, i = idx & 63;
    float inv_freq = __expf(-(float)i * 0.14391156831212788f);
    float ang = (float)s * inv_freq;
    float2 cs;
    cs.x = cosf(ang);
    cs.y = sinf(ang);
    tab[idx] = cs;
    if (idx < NC)
        bias[idx] = (idx < KOFF) ? bQ[idx] : (idx < VOFF ? bK[idx - KOFF] : bV[idx - VOFF]);
}

// ---------------- GEMM: C[M][N] = A[M][2048] * Bt[N][2048]^T + bias ----------------
// 2-phase 128x128 (768/512 blocks = full CU coverage; r9: 256-tile underfills).
// (256,3): cap regs ~170/wave -> 3 blocks/CU (r7/r8 on flash: occupancy > spill;
// inner-loop demand ~115 regs fits, any spill is epilogue-only). ROT=1: fused
// rotary epilogue for q/k cols; V cols (n0>=VOFF) write TRANSPOSED into
// vtq[vcol][s] via LDS round-trip (replaces standalone vtrans kernel).
#define BM 128
#define BN 128
#define BK 64
#define VTL 132   // vtile row stride (elems)

template <typename OutT, int ROT>
__global__ __launch_bounds__(256, 3)
void gemm_bt(const bf16* __restrict__ A, const bf16* __restrict__ Bt,
             const float* __restrict__ bias, OutT* __restrict__ C, int N,
             const float2* __restrict__ tab, bf16* __restrict__ vtq) {
    __shared__ __align__(16) char smemraw[33792];  // As|Bs (32KB) / vtile [128][132]
    bf16* As = (bf16*)smemraw;
    bf16* Bs = (bf16*)(smemraw + 16384);
    const int tid = threadIdx.x;
    const int wave = tid >> 6, lane = tid & 63;
    const int quad = lane >> 4, l15 = lane & 15;
    const int wm = (wave >> 1) * 64, wn = (wave & 1) * 64;
    const int m0 = blockIdx.y * BM, n0 = blockIdx.x * BN;

    f32x4 acc[4][4] = {};

    const bf16* gsrc = (wave < 2)
        ? A  + (size_t)(m0 + (wave & 1) * 64) * DM
        : Bt + (size_t)(n0 + (wave & 1) * 64) * DM;
    bf16* lbase = (wave < 2 ? As : Bs) + (wave & 1) * 64 * BK;
    const int lrow = lane >> 3;                          // 0..7
    const int gslot = (lane & 7) ^ lrow;                 // swizzled source slot
    const bf16* gp = gsrc + (size_t)lrow * DM + gslot * 8;

    const int rsw = l15 & 7;

    for (int k0 = 0; k0 < DM; k0 += BK) {
        __syncthreads();
        #pragma unroll
        for (int cc = 0; cc < 8; ++cc)
            load_lds16(gp + (size_t)cc * 8 * DM + k0, lbase + cc * 8 * BK);
        __syncthreads();

        #pragma unroll
        for (int ks = 0; ks < 2; ++ks) {
            bf16x8 af[4], bfr[4];
            #pragma unroll
            for (int i = 0; i < 4; ++i)
                af[i] = *(const bf16x8*)&As[(wm + i * 16 + l15) * BK + (((ks * 4 + quad) ^ rsw) * 8)];
            #pragma unroll
            for (int j = 0; j < 4; ++j)
                bfr[j] = *(const bf16x8*)&Bs[(wn + j * 16 + l15) * BK + (((ks * 4 + quad) ^ rsw) * 8)];
            #pragma unroll
            for (int i = 0; i < 4; ++i)
                #pragma unroll
                for (int j = 0; j < 4; ++j)
                    acc[i][j] = __builtin_amdgcn_mfma_f32_16x16x32_bf16(af[i], bfr[j], acc[i][j], 0, 0, 0);
        }
    }

    if (ROT && n0 >= VOFF) {
        // ---- V tile: write transposed to vtq[vcol][s] via LDS ----
        __syncthreads();                       // all waves done with As/Bs
        bf16* vtile = (bf16*)smemraw;          // [128 cols][VTL]
        #pragma unroll
        for (int i = 0; i < 4; ++i) {
            const int rl0 = wm + i * 16 + quad * 4;
            #pragma unroll
            for (int j = 0; j < 4; ++j) {
                const int cl = wn + j * 16 + l15;
                const float bv = bias[n0 + cl];
                ushort4 w;
                bf16 h;
                h = f2bf(acc[i][j][0] + bv); w.x = *(unsigned short*)&h;
                h = f2bf(acc[i][j][1] + bv); w.y = *(unsigned short*)&h;
                h = f2bf(acc[i][j][2] + bv); w.z = *(unsigned short*)&h;
                h = f2bf(acc[i][j][3] + bv); w.w = *(unsigned short*)&h;
                *(ushort4*)&vtile[cl * VTL + rl0] = w;
            }
        }
        __syncthreads();
        // coalesced-ish store: 8 lanes cover 128B of one col per pass
        #pragma unroll
        for (int p = 0; p < 4; ++p) {
            const int c = p * 32 + (tid >> 3);
            const int s = (tid & 7) * 16;
            bf16* dst = vtq + (size_t)(n0 - VOFF + c) * SEQ + m0 + s;
            const bf16* srcl = vtile + c * VTL + s;
            *(bf16x8*)dst       = *(const bf16x8*)srcl;
            *(bf16x8*)(dst + 8) = *(const bf16x8*)(srcl + 8);
        }
        return;
    }

    const bool doRot = ROT && (n0 < VOFF);
    const float scl = (n0 < KOFF) ? Q_SCALE : 1.0f;

    #pragma unroll
    for (int i = 0; i < 4; ++i) {
        int row = m0 + wm + i * 16 + quad * 4;
        #pragma unroll
        for (int j = 0; j < 4; ++j) {
            int col = n0 + wn + j * 16 + l15;
            float bv = bias[col];
            if (ROT && doRot) {
                const int ii = (col >> 1) & 63;
                const bool odd = col & 1;
                #pragma unroll
                for (int r = 0; r < 4; ++r) {
                    float v = acc[i][j][r] + bv;
                    float pv = __shfl_xor(v, 1);
                    float2 cs = tab[((row + r) << 6) + ii];
                    float o = odd ? (pv * cs.y + v * cs.x) : (v * cs.x - pv * cs.y);
                    C[(size_t)(row + r) * N + col] = (OutT)f2bf(o * scl);
                }
            } else {
                #pragma unroll
                for (int r = 0; r < 4; ++r) {
                    float val = acc[i][j][r] + bv;
                    if constexpr (sizeof(OutT) == 2)
                        C[(size_t)(row + r) * N + col] = f2bf(val);
                    else
                        C[(size_t)(row + r) * N + col] = val;
                }
            }
        }
    }
}

// ---------------- flash attention v9 (frozen from r8: 110.2 us) ----------------
// 1024 blocks x 256 thr; block = (qt, g, hp), biggest-qt-first (LPT backfill).
// 4 waves = 2 ch x 2 kh. K/V via global_load_lds, XOR involution swizzle,
// swapped QK^T + in-reg P (T12), (256,3) cap = 3 blocks/CU (occupancy > spill).
__global__ __launch_bounds__(256, 3)
void flash(const bf16* __restrict__ qkv, const bf16* __restrict__ vt,
           bf16* __restrict__ z) {
    __shared__ char smem[33280];
    bf16*  Ks  = (bf16*)smem;                    // [64][128]  = 16384 B (swizzled)
    bf16*  Vs  = (bf16*)(smem + 16384);          // [128][64]  = 16384 B (swizzled)
    float* lml = (float*)(smem + 32768);         // 4 x 32     =   512 B
    float* ob  = (float*)smem;                   // merge reuse: 2*32*128 f32 = 32768 B

    const int tid = threadIdx.x;
    const int wave = tid >> 6, lane = tid & 63;
    const int l31 = lane & 31, lh = lane >> 5;
    const int ch = wave >> 1;         // row chunk (16 rows)
    const int kh = wave & 1;          // key half (32 keys)
    const int bx = blockIdx.x;
    const int qt = 127 - (bx >> 3);   // biggest first
    const int g = (bx >> 1) & 3;      // KV group
    const int hp = bx & 1;            // head pair within group
    const int r_base = qt * 32 + ch * 16;
    const int ktmax = qt >> 1;
    const int rsw = l31 & 7;          // read-side XOR (row&7 for both QK and PV reads)

    // staging pointers (3 total; folding: krow&7 repeats every 8 rows, vdd&7 is
    // chunk-independent)
    const int krow0 = wave * 16 + (lane >> 4);          // chunk i=0 row
    const int krow1 = krow0 + 4;                        // chunk i=1 row
    const bf16* kp0 = qkv + KOFF + g * DH + (size_t)krow0 * NC + (((lane & 15) ^ (krow0 & 7)) * 8);
    const bf16* kp1 = qkv + KOFF + g * DH + (size_t)krow1 * NC + (((lane & 15) ^ (krow1 & 7)) * 8);
    const int vdd0 = wave * 32 + (lane >> 3);           // chunk i=0 d-row
    const bf16* vp0 = vt + (size_t)(g * DH + vdd0) * SEQ + (((lane & 7) ^ ((lane >> 3) & 7)) * 8);

    // Q -> registers (B operand): lane n=l31 -> q-row; k = lh*8 + s*16 + j
    bf16x8 qf[8];
    {
        const int qrow = r_base + (l31 & 15);
        const int head = g * 4 + hp * 2 + (l31 >> 4);
        const bf16* qp = qkv + (size_t)qrow * NC + head * DH + lh * 8;
        #pragma unroll
        for (int s = 0; s < 8; ++s)
            qf[s] = *(const bf16x8*)(qp + s * 16);
    }

    f32x16 o_acc[4] = {};
    float lsum = 0.0f;

    for (int kt = 0; kt <= ktmax; ++kt) {
        __syncthreads();   // all waves done reading Ks/Vs of prev iter
        load_lds16(kp0,                        Ks + (wave * 4 + 0) * 512);
        load_lds16(kp1,                        Ks + (wave * 4 + 1) * 512);
        load_lds16(kp0 + (size_t)8 * NC,       Ks + (wave * 4 + 2) * 512);
        load_lds16(kp1 + (size_t)8 * NC,       Ks + (wave * 4 + 3) * 512);
        load_lds16(vp0,                        Vs + (wave * 4 + 0) * 512);
        load_lds16(vp0 + (size_t)8 * SEQ,      Vs + (wave * 4 + 1) * 512);
        load_lds16(vp0 + (size_t)16 * SEQ,     Vs + (wave * 4 + 2) * 512);
        load_lds16(vp0 + (size_t)24 * SEQ,     Vs + (wave * 4 + 3) * 512);
        __syncthreads();   // compiler drains vmcnt(0) before barrier
        kp0 += (size_t)64 * NC; kp1 += (size_t)64 * NC; vp0 += 64;

        const int key_min = kt * 64 + kh * 32;
        if (key_min <= r_base + 15) {   // some key unmasked for this chunk
            // S^T = K Q^T : lane l31 = q-row, regs = 16 keys
            f32x16 sacc = {};
            __builtin_amdgcn_s_setprio(1);
            #pragma unroll
            for (int s = 0; s < 8; ++s) {
                bf16x8 kb = *(const bf16x8*)&Ks[(kh * 32 + l31) * 128 + (((lh + 2 * s) ^ rsw) * 8)];
                sacc = __builtin_amdgcn_mfma_f32_32x32x16_bf16(kb, qf[s], sacc, 0, 0, 0);
            }
            __builtin_amdgcn_s_setprio(0);

            const bool needmask = (key_min + 31 > r_base);
            const int qrow = r_base + (l31 & 15);
            float e[16];
            if (needmask) {   // diagonal tile only (~1 of ~33 iters)
                #pragma unroll
                for (int rg = 0; rg < 16; ++rg) {
                    const int keyg = key_min + (rg & 3) + 8 * (rg >> 2) + 4 * lh;
                    float sv = sacc[rg];
                    if (keyg > qrow) sv = -INFINITY;
                    e[rg] = exp2f(sv);
                }
            } else {
                #pragma unroll
                for (int rg = 0; rg < 16; ++rg)
                    e[rg] = exp2f(sacc[rg]);
            }
            {
                float t0 = (e[0] + e[1]) + (e[2] + e[3]);
                float t1 = (e[4] + e[5]) + (e[6] + e[7]);
                float t2 = (e[8] + e[9]) + (e[10] + e[11]);
                float t3 = (e[12] + e[13]) + (e[14] + e[15]);
                lsum += (t0 + t1) + (t2 + t3);
            }

            // P -> A fragments in-register (T12)
            bf16x8 pa[2];
            #pragma unroll
            for (int s2 = 0; s2 < 2; ++s2) {
                uint32_t wA0, wA1, wB0, wB1;
                asm("v_cvt_pk_bf16_f32 %0, %1, %2" : "=v"(wA0) : "v"(e[8*s2+0]), "v"(e[8*s2+1]));
                asm("v_cvt_pk_bf16_f32 %0, %1, %2" : "=v"(wA1) : "v"(e[8*s2+2]), "v"(e[8*s2+3]));
                asm("v_cvt_pk_bf16_f32 %0, %1, %2" : "=v"(wB0) : "v"(e[8*s2+4]), "v"(e[8*s2+5]));
                asm("v_cvt_pk_bf16_f32 %0, %1, %2" : "=v"(wB1) : "v"(e[8*s2+6]), "v"(e[8*s2+7]));
                asm volatile("v_permlane32_swap_b32 %0, %1" : "+v"(wA0), "+v"(wB0));
                asm volatile("v_permlane32_swap_b32 %0, %1" : "+v"(wA1), "+v"(wB1));
                union { uint32_t u[4]; bf16x8 v; } cvt;
                cvt.u[0] = wA0; cvt.u[1] = wA1; cvt.u[2] = wB0; cvt.u[3] = wB1;
                pa[s2] = cvt.v;
            }

            // PV: A = P fragments (in-reg), B = V^T fragments from LDS
            __builtin_amdgcn_s_setprio(1);
            #pragma unroll
            for (int nt = 0; nt < 4; ++nt) {
                #pragma unroll
                for (int s2 = 0; s2 < 2; ++s2) {
                    bf16x8 vb = *(const bf16x8*)&Vs[(nt * 32 + l31) * 64 + (((kh * 4 + lh + 2 * s2) ^ rsw) * 8)];
                    o_acc[nt] = __builtin_amdgcn_mfma_f32_32x32x16_bf16(pa[s2], vb, o_acc[nt], 0, 0, 0);
                }
            }
            __builtin_amdgcn_s_setprio(0);
        }
    }

    // merge lh halves of l in-register
    float la = lsum, lb = lsum;
    asm volatile("v_permlane32_swap_b32 %0, %1" : "+v"(la), "+v"(lb));
    const float l_tot = la + lb;   // full 32-key-half sum for q-row l31

    // ---- merge key-half partials (linear: no max alignment needed) ----
    __syncthreads();               // all compute done; Ks/Vs region free for ob
    if (lh == 0) lml[wave * 32 + l31] = l_tot;
    if (kh == 1) {
        #pragma unroll
        for (int nt = 0; nt < 4; ++nt)
            #pragma unroll
            for (int rg = 0; rg < 16; ++rg) {
                const int m = (rg & 3) + 8 * (rg >> 2) + 4 * lh;
                ob[(ch * 32 + m) * 128 + nt * 32 + l31] = o_acc[nt][rg];
            }
    }
    __syncthreads();
    if (kh == 0) {
        float invl[16];
        #pragma unroll
        for (int rg = 0; rg < 16; ++rg) {
            const int m = (rg & 3) + 8 * (rg >> 2) + 4 * lh;
            invl[rg] = 1.0f / (lml[wave * 32 + m] + lml[(wave + 1) * 32 + m]);
        }
        #pragma unroll
        for (int nt = 0; nt < 4; ++nt)
            #pragma unroll
            for (int rg = 0; rg < 16; ++rg) {
                const int m = (rg & 3) + 8 * (rg >> 2) + 4 * lh;
                float oo = o_acc[nt][rg] + ob[(ch * 32 + m) * 128 + nt * 32 + l31];
                const int row = r_base + (m & 15);
                const int col = (g * 4 + hp * 2 + (m >> 4)) * DH + nt * 32 + l31;
                z[(size_t)row * DM + col] = f2bf(oo * invl[rg]);
            }
    }
}

// ---------------- launch ----------------
extern "C" void kernel_launch(void* const* d_in, const int* in_sizes, int n_in,
                              void* d_out, int out_size, void* d_ws, size_t ws_size,
                              hipStream_t stream) {
    const float* x  = (const float*)d_in[0];
    const float* WQ = (const float*)d_in[1];
    const float* WK = (const float*)d_in[2];
    const float* WV = (const float*)d_in[3];
    const float* WO = (const float*)d_in[4];
    const float* bQ = (const float*)d_in[5];
    const float* bK = (const float*)d_in[6];
    const float* bV = (const float*)d_in[7];
    const float* bO = (const float*)d_in[8];
    float* out = (float*)d_out;

    char* ws = (char*)d_ws;
    bf16*  wt_cat = (bf16*)(ws);                  // 12,582,912
    bf16*  wt_o   = (bf16*)(ws + 12582912);       //  8,388,608
    float* bias_c = (float*)(ws + 20971520);      //  16,384 (padded)
    bf16*  qkv    = (bf16*)(ws + 20987904);       // 25,165,824
    bf16*  vt     = (bf16*)(ws + 46153728);       //  4,194,304 (written by gemm1 V-epilogue)
    bf16*  z      = (bf16*)(ws + 50348032);       // 16,777,216
    bf16*  xb     = (bf16*)(ws + 67125248);       // 16,777,216
    float2* sct   = (float2*)z;                   // 2,097,152: z region dead until
                                                  // flash; sct dead after gemm1

    xconv    <<<8192, 256, 0, stream>>>(x, xb);
    prep_wqkv<<<dim3(32, 48), 256, 0, stream>>>(WQ, WK, WV, wt_cat);
    prep_wo  <<<dim3(32, 32), 256, 0, stream>>>(WO, wt_o);
    sctab    <<<1024, 256, 0, stream>>>(sct, bQ, bK, bV, bias_c);
    gemm_bt<bf16, 1> <<<dim3(24, 32), 256, 0, stream>>>(xb, wt_cat, bias_c, qkv, NC, sct, vt);
    flash    <<<1024, 256, 0, stream>>>(qkv, vt, z);
    gemm_bt<float, 0><<<dim3(16, 32), 256, 0, stream>>>(z, wt_o, bO, out, DM, nullptr, nullptr);
}